// Round 12
// baseline (343.866 us; speedup 1.0000x reference)
//
#include <hip/hip_runtime.h>
#include <hip/hip_bf16.h>
#include <float.h>

// Problem constants (from reference)
#define N_NODES 20000
#define LATENT  512
#define HID     256
#define OUT_C   128
#define HEADS   2
#define HC      256   // HEADS*OUT_C
#define NEG_SLOPE 0.2f

typedef _Float16 half8 __attribute__((ext_vector_type(8)));  // 8 f16 = 4 VGPRs
typedef __attribute__((ext_vector_type(4))) float f32x4;

// ---------------------------------------------------------------------------
__device__ __forceinline__ ushort f2h(float v) {
    _Float16 h = (_Float16)v;
    return *(ushort*)&h;
}
__device__ __forceinline__ float h2f(ushort u) {
    _Float16 h = *(_Float16*)&u;
    return (float)h;
}

// async global->LDS DMA, 16B per lane. LDS dest is WAVE-UNIFORM base +
// lane*16 (m104/m108); per-lane scatter impossible -> XOR chunk swizzle.
__device__ __forceinline__ void gl_lds16(const ushort* g, ushort* l) {
    __builtin_amdgcn_global_load_lds(
        (const __attribute__((address_space(1))) unsigned int*)g,
        (__attribute__((address_space(3))) unsigned int*)l, 16, 0, 0);
}

// ---------------------------------------------------------------------------
// fp16 MFMA GEMM:  C = act( A*B + bias ),  fp32 accumulate.
// A [M,K] f16 row-major (over-allocated by 128 rows: OOB tile rows read
// garbage, never fault, confined to C rows >= M which are not stored).
// B TRANSPOSED: BT [N,K] f16, N % BN == 0, K % (2*BK) == 0.
// Block tile 128 x BN, 4 waves; wave tile 64 x BN/2. Double-buffered
// global_load_lds (R8: VGPR prefetch spills; R7: single buffer = zero
// overlap). R11 A/B: BK=64 (GEMM2/4) halves barrier count, 2x compute per
// barrier, vs BK=32 (GEMM1/3) — counters differentiate via LDS_Block_Size.
// Swizzle: 16B chunk c of row r stored at slot c^(r&(CR-1)), CR=BK/8;
// frag reads land 2 lanes/bank-group (free, m136).
template<int BN, int BK>
__global__ __launch_bounds__(256) void gemm_f16(
    const ushort* __restrict__ A, const ushort* __restrict__ BT,
    const float* __restrict__ bias,
    float* __restrict__ Cf, ushort* __restrict__ Ch,
    int M, int N, int K, int relu)
{
    constexpr int NI  = BN / 32;          // N-frags per wave
    constexpr int CR  = BK / 8;           // 16B chunks per LDS row
    constexpr int RPI = 64 / CR;          // rows covered per DMA instr
    constexpr int NAI = CR / 2;           // A DMA instrs per wave (128 rows)
    constexpr int NBI = BN * CR / 256;    // B DMA instrs per wave
    constexpr int KH  = BK / 32;          // K=32 MFMA passes per buffer
    constexpr int BBASE = 128 * BK;       // B tile base (shorts)
    constexpr int BUF = (128 + BN) * BK;  // shorts per buffer
    __shared__ ushort lds[2 * BUF];
    ushort* buf0 = lds;
    ushort* buf1 = lds + BUF;

    const int t = threadIdx.x;
    const int l = t & 63;
    const int w = t >> 6;
    const int wm = (w >> 1) * 64;         // wave M offset
    const int wn = (w & 1) * (BN / 2);    // wave N offset
    const int lm = l & 15;
    const int q  = l >> 4;                // k-chunk id within 32 (0..3)
    const int q4 = q * 4;                 // C frag row offset

    const int row0 = blockIdx.x * 128;
    const int col0 = blockIdx.y * BN;

    // Staging: DMA instr i = j*4+w covers tile rows i*RPI..+RPI; lane l ->
    // row += l/CR, slot l%CR; global chunk = slot ^ (row_in_instr&(CR-1)).
    // Each instr writes 1 KB at tile_base + i*512 shorts.
    const int rli = l / CR;
    const int gch = ((l % CR) ^ (rli & (CR - 1)));
    const ushort* gA[NAI];
    int dA[NAI];
    #pragma unroll
    for (int j = 0; j < NAI; ++j) {
        const int i = j * 4 + w;
        gA[j] = A + (size_t)(row0 + i * RPI + rli) * K + gch * 8;
        dA[j] = i * 512;
    }
    const ushort* gB[NBI];
    int dB[NBI];
    #pragma unroll
    for (int j = 0; j < NBI; ++j) {
        const int i = j * 4 + w;
        gB[j] = BT + (size_t)(col0 + i * RPI + rli) * K + gch * 8;
        dB[j] = BBASE + i * 512;
    }

    const f32x4 zf = {0.f, 0.f, 0.f, 0.f};
    f32x4 acc[4][NI];
    #pragma unroll
    for (int i = 0; i < 4; ++i)
        #pragma unroll
        for (int j = 0; j < NI; ++j) acc[i][j] = zf;

    auto issue = [&](int kk, ushort* B) {
        #pragma unroll
        for (int j = 0; j < NAI; ++j) gl_lds16(gA[j] + kk, B + dA[j]);
        #pragma unroll
        for (int j = 0; j < NBI; ++j) gl_lds16(gB[j] + kk, B + dB[j]);
    };

    auto compute = [&](const ushort* B) {
        #pragma unroll
        for (int kh = 0; kh < KH; ++kh) {
            const int csw = (((kh * 4 + q) ^ (lm & (CR - 1))) << 3);
            half8 bf[NI];
            #pragma unroll
            for (int ni = 0; ni < NI; ++ni)
                bf[ni] = *(const half8*)&B[BBASE + (wn + ni * 16 + lm) * BK + csw];
            #pragma unroll
            for (int mi = 0; mi < 4; ++mi) {
                half8 af = *(const half8*)&B[(wm + mi * 16 + lm) * BK + csw];
                #pragma unroll
                for (int ni = 0; ni < NI; ++ni)
                    acc[mi][ni] = __builtin_amdgcn_mfma_f32_16x16x32_f16(
                        af, bf[ni], acc[mi][ni], 0, 0, 0);
            }
        }
    };

    issue(0, buf0);
    __syncthreads();
    for (int k0 = 0; k0 < K; k0 += 2 * BK) {
        issue(k0 + BK, buf1);
        compute(buf0);
        __syncthreads();
        if (k0 + 2 * BK < K) issue(k0 + 2 * BK, buf0);
        compute(buf1);
        __syncthreads();
    }

    // Epilogue. C/D frag: col = lane&15, row = (lane>>4)*4 + reg  [m89/m91]
    #pragma unroll
    for (int mi = 0; mi < 4; ++mi) {
        #pragma unroll
        for (int ni = 0; ni < NI; ++ni) {
            const int col = col0 + wn + ni * 16 + lm;
            const float bv = bias ? bias[col] : 0.f;
            #pragma unroll
            for (int r = 0; r < 4; ++r) {
                const int row = row0 + wm + mi * 16 + q4 + r;
                if (row >= M) continue;
                float v = acc[mi][ni][r] + bv;
                if (relu) v = fmaxf(v, 0.f);
                const size_t idx = (size_t)row * N + col;
                if (Cf) Cf[idx] = v;
                if (Ch) Ch[idx] = f2h(v);
            }
        }
    }
}

// ---------------------------------------------------------------------------
// fp32 -> f16 convert (x4) + fused zeroing of deg/cursor (independent data)
__global__ __launch_bounds__(256) void cvt_zero_kernel(
    const float* __restrict__ x, ushort* __restrict__ o, int n4,
    int* deg, int* cursor, int n)
{
    int i = blockIdx.x * 256 + threadIdx.x;
    if (i < n) { deg[i] = 0; cursor[i] = 0; }
    if (i >= n4) return;
    float4 v = ((const float4*)x)[i];
    ((ushort4*)o)[i] = make_ushort4(f2h(v.x), f2h(v.y), f2h(v.z), f2h(v.w));
}

// ---------------------------------------------------------------------------
// Blocks [0,2048): 4 weights W [K,N] fp32 -> WT [N,K] f16 (2^17 elems each).
// Blocks [2048,..): dst histogram (deg zeroed by the PRIOR cvt_zero launch).
__global__ __launch_bounds__(256) void transpose_cvt4_hist_kernel(
    const float* __restrict__ W1, const float* __restrict__ W2,
    const float* __restrict__ Wg, const float* __restrict__ W3,
    ushort* __restrict__ T1, ushort* __restrict__ T2,
    ushort* __restrict__ Tg, ushort* __restrict__ T3,
    const int* __restrict__ dst, int* deg, int E_real, int ET)
{
    if (blockIdx.x >= 2048) {
        int e = (blockIdx.x - 2048) * 256 + threadIdx.x;
        if (e >= ET) return;
        int d = (e < E_real) ? dst[e] : (e - E_real);
        atomicAdd(&deg[d], 1);
        return;
    }
    int idx = blockIdx.x * 256 + threadIdx.x;
    int which = idx >> 17, i = idx & 131071;
    const float* W; ushort* T; int K, N;
    if (which == 0)      { W = W1; T = T1; K = 512; N = 256; }
    else if (which == 1) { W = W2; T = T2; K = 256; N = 512; }
    else if (which == 2) { W = Wg; T = Tg; K = 512; N = 256; }
    else                 { W = W3; T = T3; K = 256; N = 512; }
    int k = i / N, n = i - k * N;
    T[(size_t)n * K + k] = f2h(W[i]);
}

// ---------------------------------------------------------------------------
// One WAVE per node. Lane l: head h=l>>5, 4 channels via ushort4 (8B/lane).
__global__ __launch_bounds__(256) void att_kernel(
    const ushort* __restrict__ xp, const float* __restrict__ att_src,
    const float* __restrict__ att_dst,
    float* __restrict__ a_src, float* __restrict__ a_dst, int n)
{
    int node = (blockIdx.x * 256 + threadIdx.x) >> 6;
    int lane = threadIdx.x & 63;
    if (node >= n) return;
    int h = lane >> 5, lh = lane & 31;
    int c = h * OUT_C + lh * 4;
    const ushort4 v = *(const ushort4*)(xp + (size_t)node * HC + c);
    const float4 as = *(const float4*)(att_src + c);
    const float4 ad = *(const float4*)(att_dst + c);
    float x0 = h2f(v.x), x1 = h2f(v.y), x2 = h2f(v.z), x3 = h2f(v.w);
    float s1 = x0 * as.x + x1 * as.y + x2 * as.z + x3 * as.w;
    float s2 = x0 * ad.x + x1 * ad.y + x2 * ad.z + x3 * ad.w;
    #pragma unroll
    for (int off = 16; off > 0; off >>= 1) {
        s1 += __shfl_xor(s1, off);
        s2 += __shfl_xor(s2, off);
    }
    if (lh == 0) { a_src[2 * node + h] = s1; a_dst[2 * node + h] = s2; }
}

// ---------------------------------------------------------------------------
// Exclusive scan deg[0..n) -> rowptr[0..n]; single block, 256 threads.
__global__ __launch_bounds__(256) void scan_kernel(
    const int* __restrict__ deg, int* __restrict__ rowptr, int n)
{
    __shared__ int part[256];
    const int t = threadIdx.x;
    const int chunk = (n + 255) / 256;
    const int lo = t * chunk;
    const int hi = min(lo + chunk, n);
    int s = 0;
    for (int i = lo; i < hi; ++i) s += deg[i];
    part[t] = s;
    __syncthreads();
    #pragma unroll
    for (int off = 1; off < 256; off <<= 1) {
        int add = (t >= off) ? part[t - off] : 0;
        __syncthreads();
        part[t] += add;
        __syncthreads();
    }
    int run = part[t] - s;   // exclusive prefix of this thread's chunk
    for (int i = lo; i < hi; ++i) { rowptr[i] = run; run += deg[i]; }
    if (t == 255) rowptr[n] = part[255];
}

__global__ __launch_bounds__(256) void scatter_kernel(
    const int* __restrict__ src, const int* __restrict__ dst,
    const int* __restrict__ rowptr, int* cursor,
    int* __restrict__ sorted_src, int E_real, int ET)
{
    int e = blockIdx.x * blockDim.x + threadIdx.x;
    if (e >= ET) return;
    int s, d;
    if (e < E_real) { s = src[e]; d = dst[e]; }
    else            { s = e - E_real; d = s; }
    int pos = rowptr[d] + atomicAdd(&cursor[d], 1);
    sorted_src[pos] = s;
}

// ---------------------------------------------------------------------------
// One WAVE per dst node; lane owns 4 channels; head = lane>>5. xp is f16
// (ushort4 gather = 8 B/lane, 512 B coalesced per row). R11: inner loop
// unrolled x4 with batched independent gathers for memory-level parallelism.
__global__ __launch_bounds__(64) void gat_aggregate(
    const int* __restrict__ rowptr, const int* __restrict__ sorted_src,
    const float* __restrict__ a_src, const float* __restrict__ a_dst,
    const ushort* __restrict__ xp, const float* __restrict__ bias_g,
    ushort* __restrict__ xg)
{
    __shared__ float s_w[2][64];
    __shared__ int   s_off[64];

    const int d = blockIdx.x;
    const int lane = threadIdx.x;
    const int h = lane >> 5;
    const int start = rowptr[d], end = rowptr[d + 1];

    const float ad0 = a_dst[2 * d + 0];
    const float ad1 = a_dst[2 * d + 1];

    float m0 = -FLT_MAX, m1 = -FLT_MAX;
    for (int e = start + lane; e < end; e += 64) {
        int s = sorted_src[e];
        float v0 = a_src[2 * s + 0] + ad0;
        float v1 = a_src[2 * s + 1] + ad1;
        v0 = (v0 > 0.f) ? v0 : NEG_SLOPE * v0;
        v1 = (v1 > 0.f) ? v1 : NEG_SLOPE * v1;
        m0 = fmaxf(m0, v0);
        m1 = fmaxf(m1, v1);
    }
    #pragma unroll
    for (int off = 32; off > 0; off >>= 1) {
        m0 = fmaxf(m0, __shfl_xor(m0, off));
        m1 = fmaxf(m1, __shfl_xor(m1, off));
    }

    float4 acc = make_float4(0.f, 0.f, 0.f, 0.f);
    float denom = 0.f;
    const int cl = 4 * lane;
    for (int e0 = start; e0 < end; e0 += 64) {
        int cnt = min(64, end - e0);
        if (lane < cnt) {
            int s = sorted_src[e0 + lane];
            float v0 = a_src[2 * s + 0] + ad0;
            float v1 = a_src[2 * s + 1] + ad1;
            v0 = (v0 > 0.f) ? v0 : NEG_SLOPE * v0;
            v1 = (v1 > 0.f) ? v1 : NEG_SLOPE * v1;
            s_w[0][lane] = expf(v0 - m0);
            s_w[1][lane] = expf(v1 - m1);
            s_off[lane] = s * HC;
        }
        __syncthreads();
        int j = 0;
        for (; j + 4 <= cnt; j += 4) {
            const ushort4 v0 = *(const ushort4*)(xp + s_off[j + 0] + cl);
            const ushort4 v1 = *(const ushort4*)(xp + s_off[j + 1] + cl);
            const ushort4 v2 = *(const ushort4*)(xp + s_off[j + 2] + cl);
            const ushort4 v3 = *(const ushort4*)(xp + s_off[j + 3] + cl);
            const float w0 = s_w[h][j + 0], w1 = s_w[h][j + 1];
            const float w2 = s_w[h][j + 2], w3 = s_w[h][j + 3];
            denom += (w0 + w1) + (w2 + w3);
            acc.x += w0 * h2f(v0.x) + w1 * h2f(v1.x) + w2 * h2f(v2.x) + w3 * h2f(v3.x);
            acc.y += w0 * h2f(v0.y) + w1 * h2f(v1.y) + w2 * h2f(v2.y) + w3 * h2f(v3.y);
            acc.z += w0 * h2f(v0.z) + w1 * h2f(v1.z) + w2 * h2f(v2.z) + w3 * h2f(v3.z);
            acc.w += w0 * h2f(v0.w) + w1 * h2f(v1.w) + w2 * h2f(v2.w) + w3 * h2f(v3.w);
        }
        for (; j < cnt; ++j) {
            const float w = s_w[h][j];
            const ushort4 v = *(const ushort4*)(xp + s_off[j] + cl);
            denom += w;
            acc.x += w * h2f(v.x); acc.y += w * h2f(v.y);
            acc.z += w * h2f(v.z); acc.w += w * h2f(v.w);
        }
        __syncthreads();
    }

    float inv = 1.f / fmaxf(denom, 1e-16f);
    float4 bg = *(const float4*)(bias_g + cl);
    const size_t base = ((size_t)d * HC + cl) >> 2;
    ((ushort4*)xg)[base] = make_ushort4(
        f2h(acc.x * inv + bg.x), f2h(acc.y * inv + bg.y),
        f2h(acc.z * inv + bg.z), f2h(acc.w * inv + bg.w));
}

// ---------------------------------------------------------------------------
extern "C" void kernel_launch(void* const* d_in, const int* in_sizes, int n_in,
                              void* d_out, int out_size, void* d_ws, size_t ws_size,
                              hipStream_t stream)
{
    const float* z       = (const float*)d_in[0];
    const int*   ei      = (const int*)d_in[1];    // [2,E] int32
    const float* W1      = (const float*)d_in[2];
    const float* b1      = (const float*)d_in[3];
    const float* W2      = (const float*)d_in[4];
    const float* b2      = (const float*)d_in[5];
    const float* Wg      = (const float*)d_in[6];
    const float* att_src = (const float*)d_in[7];
    const float* att_dst = (const float*)d_in[8];
    const float* bias_g  = (const float*)d_in[9];
    const float* W3      = (const float*)d_in[10];
    const float* b3      = (const float*)d_in[11];
    float* out = (float*)d_out;

    const int n = N_NODES;
    const int E_real = in_sizes[1] / 2;
    const int ET = E_real + n;
    const int* src = ei;
    const int* dst = ei + E_real;

    // Workspace. GEMM-A arrays over-allocated by 128 rows (DMA staging of
    // the last partial tile reads garbage, never faults).
    // Aliases: z_f16 (dead after GEMM1) = x2_f16; x1_f16 (dead after GEMM2) = xg.
    char* p = (char*)d_ws;
    auto alloc = [&](size_t bytes) {
        char* r = p;
        p += (bytes + 63) & ~(size_t)63;
        return r;
    };
    const int np = n + 128;
    ushort* z_f16  = (ushort*)alloc((size_t)np * LATENT * 2);  // 20.6 MB
    ushort* x1_f16 = (ushort*)alloc((size_t)np * HID * 2);     // 10.3 MB
    ushort* xp_f16 = (ushort*)alloc((size_t)n * HC * 2);       // 10.2 MB
    ushort* W1T = (ushort*)alloc((size_t)LATENT * HID * 2);
    ushort* W2T = (ushort*)alloc((size_t)HID * 512 * 2);
    ushort* WgT = (ushort*)alloc((size_t)512 * HC * 2);
    ushort* W3T = (ushort*)alloc((size_t)HC * 512 * 2);
    float* a_src = (float*)alloc((size_t)2 * n * 4);
    float* a_dst = (float*)alloc((size_t)2 * n * 4);
    int* deg        = (int*)alloc((size_t)n * 4);
    int* rowptr     = (int*)alloc(((size_t)n + 1) * 4);
    int* cursor     = (int*)alloc((size_t)n * 4);
    int* sorted_src = (int*)alloc((size_t)ET * 4);
    ushort* x2_f16 = z_f16;    // reuse (512 halfs/row, same as z)
    ushort* xg_f16 = x1_f16;   // reuse (256 halfs/row, same as x1)

    const int gm128 = (n + 127) / 128;   // 157
    const int histb = (ET + 255) / 256;

    // prologue: z->f16 (+ deg/cursor zero), weights->f16T (+ histogram), CSR
    cvt_zero_kernel<<<(n * LATENT / 4 + 255) / 256, 256, 0, stream>>>(
        z, z_f16, n * LATENT / 4, deg, cursor, n);
    transpose_cvt4_hist_kernel<<<2048 + histb, 256, 0, stream>>>(
        W1, W2, Wg, W3, W1T, W2T, WgT, W3T, dst, deg, E_real, ET);
    scan_kernel<<<1, 256, 0, stream>>>(deg, rowptr, n);
    scatter_kernel<<<histb, 256, 0, stream>>>(
        src, dst, rowptr, cursor, sorted_src, E_real, ET);

    // GEMM1: x1 = relu(z @ W1 + b1)   [20000,512]x[512,256]  BK=32
    gemm_f16<64, 32><<<dim3(gm128, HID / 64), 256, 0, stream>>>(
        z_f16, W1T, b1, nullptr, x1_f16, n, HID, LATENT, 1);
    // GEMM2: x2 = relu(x1 @ W2 + b2)  [20000,256]x[256,512]  BK=64 (A/B)
    gemm_f16<64, 64><<<dim3(gm128, 512 / 64), 256, 0, stream>>>(
        x1_f16, W2T, b2, nullptr, x2_f16, n, 512, HID, 1);
    // GEMM3: xp = x2 @ Wg             [20000,512]x[512,256]  BK=32
    gemm_f16<64, 32><<<dim3(gm128, HC / 64), 256, 0, stream>>>(
        x2_f16, WgT, nullptr, nullptr, xp_f16, n, HC, 512, 0);

    // attention logits (one wave per node, vectorized)
    att_kernel<<<(n * 64 + 255) / 256, 256, 0, stream>>>(
        xp_f16, att_src, att_dst, a_src, a_dst, n);
    // softmax + aggregate -> xg (f16)
    gat_aggregate<<<n, 64, 0, stream>>>(
        rowptr, sorted_src, a_src, a_dst, xp_f16, bias_g, xg_f16);

    // GEMM4: out = xg @ W3 + b3       [20000,256]x[256,512]  BK=64 -> fp32
    gemm_f16<64, 64><<<dim3(gm128, 512 / 64), 256, 0, stream>>>(
        xg_f16, W3T, b3, out, nullptr, n, 512, HC, 0);
}